// Round 7
// baseline (206.292 us; speedup 1.0000x reference)
//
#include <hip/hip_runtime.h>
#include <hip/hip_bf16.h>

#define S_LEN   2048
#define D_MODEL 768
#define NH      12
#define HD      64
#define NI      6
#define S2      2046
#define BB      2
#define NCH     8
#define CHK     256   // keys per chunk (NCH*CHK == S_LEN)

typedef unsigned short ushort_t;
typedef __attribute__((ext_vector_type(8))) short short8v;   // 8 bf16 = 16B
typedef __attribute__((ext_vector_type(4))) float f32x4;     // MFMA C/D frag

__device__ __forceinline__ unsigned short bf16_rne(float x) {
    union { float f; unsigned int u; } c; c.f = x;
    unsigned int u = c.u + 0x7fffu + ((c.u >> 16) & 1u);
    return (unsigned short)(u >> 16);
}
__device__ __forceinline__ float bf16_f(unsigned short h) {
    union { unsigned int u; float f; } c; c.u = ((unsigned int)h) << 16;
    return c.f;
}

__device__ __forceinline__ void gload16(const ushort_t* g, ushort_t* l) {
    __builtin_amdgcn_global_load_lds(
        (const __attribute__((address_space(1))) void*)g,
        (__attribute__((address_space(3))) void*)l, 16, 0, 0);
}

// -------- combined fp32->bf16 convert (QKV + weights) + vs zero-fill --------
struct CvtAll {
    const float* Q; const float* K; const float* V;
    const float* Wq; const float* Wk; const float* Wv; const float* Wo;
    ushort_t* Qc; ushort_t* Kc; ushort_t* Vc;
    ushort_t* Wqc; ushort_t* Wkc; ushort_t* Wvc; ushort_t* Woc;
    float* vs;
};

__global__ __launch_bounds__(256) void cvt_all(CvtAll a) {
    const int z = blockIdx.z;
    const int tid = threadIdx.x;
    if (z == 4) {
        if (blockIdx.x == 0)
            for (int i = tid; i < BB * D_MODEL; i += 256) a.vs[i] = 0.f;
        return;
    }
    const float* s; ushort_t* d; long i;
    if (z < 3) {
        s = (z == 0) ? a.Q : (z == 1) ? a.K : a.V;
        d = (z == 0) ? a.Qc : (z == 1) ? a.Kc : a.Vc;
        i = ((long)blockIdx.x * 256 + tid) * 8;
    } else {
        const long WSZ = (long)D_MODEL * D_MODEL;
        long f = ((long)blockIdx.x * 256 + tid) * 8;
        if (f >= 4 * WSZ) return;
        const int which = (int)(f / WSZ);
        i = f % WSZ;
        s = (which == 0) ? a.Wq : (which == 1) ? a.Wk : (which == 2) ? a.Wv : a.Wo;
        d = (which == 0) ? a.Wqc : (which == 1) ? a.Wkc : (which == 2) ? a.Wvc : a.Woc;
    }
    float4 v0 = *(const float4*)&s[i];
    float4 v1 = *(const float4*)&s[i + 4];
    short8v o;
    o[0] = (short)bf16_rne(v0.x); o[1] = (short)bf16_rne(v0.y);
    o[2] = (short)bf16_rne(v0.z); o[3] = (short)bf16_rne(v0.w);
    o[4] = (short)bf16_rne(v1.x); o[5] = (short)bf16_rne(v1.y);
    o[6] = (short)bf16_rne(v1.z); o[7] = (short)bf16_rne(v1.w);
    *(short8v*)&d[i] = o;
}

// ---------------- bf16 MFMA NT GEMM: C[M,N] = A[M,K] * W[N,K]^T ----------
// 64x128 tile, BK=32, ring-4 LDS, depth-3 prefetch with counted vmcnt(6),
// XCD-chunked bijective block swizzle. Optional fused V column-sum epilogue.
struct GemmArgs { const ushort_t* A; const ushort_t* W; ushort_t* C; float* Cf; float* vs; };

constexpr int GK = 768, GN = 768, GBK = 32, GNT = GK / GBK;   // 24 K-steps
constexpr int GX = 6, GY = 64;                                // grid x,y

__global__ __launch_bounds__(256) void bf16_gemm_nt(GemmArgs g0, GemmArgs g1, GemmArgs g2) {
    // bijective XCD-chunked swizzle (nwg % 8 == 0 for both 1152 and 384)
    const int nwg = GX * GY * gridDim.z;
    int flat = (blockIdx.z * GY + blockIdx.y) * GX + blockIdx.x;
    flat = (flat & 7) * (nwg >> 3) + (flat >> 3);
    const int bz = flat / (GX * GY);
    const int rem = flat - bz * (GX * GY);
    const int by = rem / GX;
    const int bx = rem - by * GX;

    GemmArgs g = (bz == 0) ? g0 : ((bz == 1) ? g1 : g2);

    __shared__ ushort_t As[4][2048];   // 64 rows x 32 bf16 per buffer (4KB)
    __shared__ ushort_t Bs[4][4096];   // 128 rows x 32 bf16 per buffer (8KB)

    const int tid  = threadIdx.x;
    const int lane = tid & 63;
    const int w    = tid >> 6;
    const int wm   = w & 1;            // 2x2 wave grid; each wave 32x64 out
    const int wn   = w >> 1;
    const int bm   = by * 64;
    const int bn   = bx * 128;
    const int fr   = lane & 15;
    const int blkr = lane >> 4;        // logical 16B-block (k/8)

    f32x4 acc[2][4];
    #pragma unroll
    for (int i = 0; i < 2; ++i)
        #pragma unroll
        for (int j = 0; j < 4; ++j)
            acc[i][j] = (f32x4){0.f, 0.f, 0.f, 0.f};

    const int row0 = tid >> 2;                      // 0..63
    const int blk0 = (tid & 3) ^ ((row0 >> 1) & 3); // inverse-swizzled source blk
    const ushort_t* Ag  = g.A + (size_t)(bm + row0) * GK + blk0 * 8;
    const ushort_t* Bg0 = g.W + (size_t)(bn + row0) * GK + blk0 * 8;
    const ushort_t* Bg1 = g.W + (size_t)(bn + row0 + 64) * GK + blk0 * 8;
    const int l0 = w * 512;            // wave-uniform LDS base (shorts)

    int aoff[2], boff[4];
    #pragma unroll
    for (int i = 0; i < 2; ++i) {
        const int ra = wm * 32 + i * 16 + fr;
        aoff[i] = (ra * 4 + (blkr ^ ((ra >> 1) & 3))) * 8;
    }
    #pragma unroll
    for (int j = 0; j < 4; ++j) {
        const int rb = wn * 64 + j * 16 + fr;
        boff[j] = (rb * 4 + (blkr ^ ((rb >> 1) & 3))) * 8;
    }

    // prologue: stage t=0,1,2 (3 loads each -> 9 in flight)
    #pragma unroll
    for (int t = 0; t < 3; ++t) {
        const int ko = t * GBK;
        gload16(Ag + ko, &As[t][l0]);
        gload16(Bg0 + ko, &Bs[t][l0]);
        gload16(Bg1 + ko, &Bs[t][2048 + l0]);
    }

    for (int t = 0; t < GNT; ++t) {
        // wait for stage(t) only; deeper stages stay in flight across barrier
        if (t < GNT - 2)      asm volatile("s_waitcnt vmcnt(6)" ::: "memory");
        else if (t == GNT - 2) asm volatile("s_waitcnt vmcnt(3)" ::: "memory");
        else                  asm volatile("s_waitcnt vmcnt(0)" ::: "memory");
        __builtin_amdgcn_s_barrier();

        if (t + 3 < GNT) {
            const int ko = (t + 3) * GBK;
            const int nb = (t + 3) & 3;
            gload16(Ag + ko, &As[nb][l0]);
            gload16(Bg0 + ko, &Bs[nb][l0]);
            gload16(Bg1 + ko, &Bs[nb][2048 + l0]);
        }

        const ushort_t* as = As[t & 3];
        const ushort_t* bs = Bs[t & 3];
        short8v a[2], b[4];
        #pragma unroll
        for (int i = 0; i < 2; ++i) a[i] = *(const short8v*)&as[aoff[i]];
        #pragma unroll
        for (int j = 0; j < 4; ++j) b[j] = *(const short8v*)&bs[boff[j]];
        #pragma unroll
        for (int i = 0; i < 2; ++i)
            #pragma unroll
            for (int j = 0; j < 4; ++j)
                acc[i][j] = __builtin_amdgcn_mfma_f32_16x16x32_bf16(a[i], b[j], acc[i][j], 0, 0, 0);
    }

    const int crow0 = bm + wm * 32 + ((lane >> 4) << 2);
    const int ccol0 = bn + wn * 64 + fr;
    if (g.Cf) {
        #pragma unroll
        for (int i = 0; i < 2; ++i)
            #pragma unroll
            for (int j = 0; j < 4; ++j)
                #pragma unroll
                for (int r = 0; r < 4; ++r)
                    g.Cf[(size_t)(crow0 + i * 16 + r) * GN + ccol0 + j * 16] = acc[i][j][r];
    } else {
        #pragma unroll
        for (int i = 0; i < 2; ++i)
            #pragma unroll
            for (int j = 0; j < 4; ++j)
                #pragma unroll
                for (int r = 0; r < 4; ++r)
                    g.C[(size_t)(crow0 + i * 16 + r) * GN + ccol0 + j * 16] = bf16_rne(acc[i][j][r]);
        if (g.vs) {   // fused V column-sum over bf16-rounded outputs
            const int bsel = (bm >= S_LEN) ? 1 : 0;
            #pragma unroll
            for (int j = 0; j < 4; ++j) {
                float part = 0.f;
                #pragma unroll
                for (int i = 0; i < 2; ++i)
                    #pragma unroll
                    for (int r = 0; r < 4; ++r)
                        part += bf16_f(bf16_rne(acc[i][j][r]));
                atomicAdd(&g.vs[bsel * D_MODEL + ccol0 + j * 16], part);
            }
        }
    }
}

// ---------------- sparse rows (pos = 1 .. 2046), 2 rows per block ----------
__global__ __launch_bounds__(768) void sparse_attn(
    const ushort_t* __restrict__ q, const ushort_t* __restrict__ k, const ushort_t* __restrict__ v,
    const float* __restrict__ vsum, const int* __restrict__ idx,
    ushort_t* __restrict__ ao) {
    const int i0 = blockIdx.x * 2;   // idx rows i0, i0+1 -> pos i0+1, i0+2
    const int b = blockIdx.y;
    const int c = threadIdx.x;       // channel 0..767 (wave == head)

    int id[2][NI];
    #pragma unroll
    for (int r = 0; r < 2; ++r)
        #pragma unroll
        for (int j = 0; j < NI; ++j) id[r][j] = idx[(i0 + r) * NI + j];
    bool dup[2][NI];
    #pragma unroll
    for (int r = 0; r < 2; ++r)
        #pragma unroll
        for (int j = 0; j < NI; ++j) {
            bool d = false;
            #pragma unroll
            for (int j2 = 0; j2 < NI; ++j2)
                if (j2 < j) d = d || (id[r][j2] == id[r][j]);
            dup[r][j] = d;
        }

    const size_t rb0 = ((size_t)(b * S_LEN + i0 + 1)) * D_MODEL + c;
    const float qv0 = bf16_f(q[rb0]);
    const float qv1 = bf16_f(q[rb0 + D_MODEL]);

    float kv[2][NI], vv[2][NI];
    #pragma unroll
    for (int r = 0; r < 2; ++r)
        #pragma unroll
        for (int j = 0; j < NI; ++j) {
            const size_t kb = ((size_t)(b * S_LEN + id[r][j])) * D_MODEL + c;
            kv[r][j] = bf16_f(k[kb]);
            vv[r][j] = bf16_f(v[kb]);
        }

    float p[2][NI];
    #pragma unroll
    for (int j = 0; j < NI; ++j) { p[0][j] = qv0 * kv[0][j]; p[1][j] = qv1 * kv[1][j]; }

    #pragma unroll
    for (int off = 32; off; off >>= 1) {
        #pragma unroll
        for (int r = 0; r < 2; ++r)
            #pragma unroll
            for (int j = 0; j < NI; ++j) p[r][j] += __shfl_xor(p[r][j], off);
    }

    const float vsc = vsum[b * D_MODEL + c];
    #pragma unroll
    for (int r = 0; r < 2; ++r) {
        float acc = vsc;
        float Z = 0.f;
        int u = 0;
        #pragma unroll
        for (int j = 0; j < NI; ++j) {
            if (dup[r][j]) continue;
            float e = expf(p[r][j] * 0.125f);
            Z += e;
            u += 1;
            acc += (e - 1.f) * vv[r][j];
        }
        Z += (float)(S_LEN - u);
        ao[rb0 + (size_t)r * D_MODEL] = bf16_rne(acc / Z);
    }
}

// ---------------- global rows: split-K partials ----------------
__global__ __launch_bounds__(256) void global_attn_part(
    const ushort_t* __restrict__ q, const ushort_t* __restrict__ k, const ushort_t* __restrict__ v,
    float* __restrict__ part) {
    const int ch = blockIdx.x;
    const int rowsel = blockIdx.y;
    const int row = rowsel ? (S_LEN - 1) : 0;
    const int hb = blockIdx.z;
    const int h = hb % NH;
    const int b = hb / NH;
    const int tid = threadIdx.x;

    __shared__ float qs[HD];
    __shared__ float ps[CHK];
    __shared__ float red[8];
    __shared__ float redv[32][72];   // padded row stride

    if (tid < HD) qs[tid] = bf16_f(q[((size_t)(b * S_LEN + row)) * D_MODEL + h * HD + tid]);
    __syncthreads();

    const int t = ch * CHK + tid;
    const ushort_t* kp = &k[((size_t)(b * S_LEN + t)) * D_MODEL + h * HD];
    float s = 0.f;
    #pragma unroll
    for (int dd = 0; dd < 8; ++dd) {
        short8v kk = *(const short8v*)&kp[dd * 8];
        #pragma unroll
        for (int e = 0; e < 8; ++e)
            s += qs[dd * 8 + e] * bf16_f((unsigned short)kk[e]);
    }
    s *= 0.125f;

    float m = s;
    #pragma unroll
    for (int off = 32; off; off >>= 1) m = fmaxf(m, __shfl_xor(m, off));
    if ((tid & 63) == 0) red[tid >> 6] = m;
    __syncthreads();
    m = fmaxf(fmaxf(red[0], red[1]), fmaxf(red[2], red[3]));

    float e = expf(s - m);
    ps[tid] = e;
    float zp = e;
    #pragma unroll
    for (int off = 32; off; off >>= 1) zp += __shfl_xor(zp, off);
    if ((tid & 63) == 0) red[4 + (tid >> 6)] = zp;
    __syncthreads();
    const float E = red[4] + red[5] + red[6] + red[7];

    const int g8 = tid >> 3;          // 0..31
    const int d8 = (tid & 7) * 8;     // 0,8,...,56
    float a8[8] = {};
    for (int tt = g8; tt < CHK; tt += 32) {
        const float wgt = ps[tt];
        short8v v8 = *(const short8v*)&v[((size_t)(b * S_LEN + ch * CHK + tt)) * D_MODEL + h * HD + d8];
        #pragma unroll
        for (int e2 = 0; e2 < 8; ++e2)
            a8[e2] += wgt * bf16_f((unsigned short)v8[e2]);
    }
    #pragma unroll
    for (int e2 = 0; e2 < 8; ++e2) redv[g8][d8 + e2] = a8[e2];
    __syncthreads();
    if (tid < HD) {
        float o = 0.f;
        #pragma unroll
        for (int gg = 0; gg < 32; ++gg) o += redv[gg][tid];
        float* pr = part + ((size_t)((hb * 2 + rowsel) * NCH + ch)) * (HD + 2);
        pr[2 + tid] = o;
        if (tid == 0) { pr[0] = m; pr[1] = E; }
    }
}

__global__ __launch_bounds__(64) void global_attn_fin(
    const float* __restrict__ part, ushort_t* __restrict__ ao) {
    const int rb = blockIdx.x;
    const int rowsel = rb & 1;
    const int hb = rb >> 1;
    const int h = hb % NH;
    const int b = hb / NH;
    const int row = rowsel ? (S_LEN - 1) : 0;
    const int d = threadIdx.x;

    const float* pr = part + (size_t)rb * NCH * (HD + 2);
    float M = -1e30f;
    #pragma unroll
    for (int c = 0; c < NCH; ++c) M = fmaxf(M, pr[c * (HD + 2)]);
    float Z = 0.f, acc = 0.f;
    #pragma unroll
    for (int c = 0; c < NCH; ++c) {
        float wgt = expf(pr[c * (HD + 2)] - M);
        Z   += pr[c * (HD + 2) + 1] * wgt;
        acc += pr[c * (HD + 2) + 2 + d] * wgt;
    }
    ao[((size_t)(b * S_LEN + row)) * D_MODEL + h * HD + d] = bf16_rne(acc / Z);
}

// ---------------- launch ----------------
extern "C" void kernel_launch(void* const* d_in, const int* in_sizes, int n_in,
                              void* d_out, int out_size, void* d_ws, size_t ws_size,
                              hipStream_t stream) {
    const float* Q  = (const float*)d_in[0];
    const float* K  = (const float*)d_in[1];
    const float* V  = (const float*)d_in[2];
    const float* Wq = (const float*)d_in[3];
    const float* Wk = (const float*)d_in[4];
    const float* Wv = (const float*)d_in[5];
    const float* Wo = (const float*)d_in[6];
    const int*  idx = (const int*)d_in[7];
    float* out = (float*)d_out;

    const size_t SZ  = (size_t)BB * S_LEN * D_MODEL;   // 3,145,728
    const size_t WSZ = (size_t)D_MODEL * D_MODEL;      // 589,824

    ushort_t* Qc  = (ushort_t*)d_ws;
    ushort_t* Kc  = Qc  + SZ;
    ushort_t* Vc  = Kc  + SZ;
    ushort_t* Wqc = Vc  + SZ;
    ushort_t* Wkc = Wqc + WSZ;
    ushort_t* Wvc = Wkc + WSZ;
    ushort_t* Woc = Wvc + WSZ;
    ushort_t* qb  = Woc + WSZ;
    ushort_t* kb  = qb  + SZ;
    ushort_t* vb  = kb  + SZ;
    ushort_t* ao  = vb  + SZ;
    float* vs   = (float*)(ao + SZ);
    float* part = vs + BB * D_MODEL;

    {   // one conversion + zero-fill dispatch
        CvtAll a{Q, K, V, Wq, Wk, Wv, Wo, Qc, Kc, Vc, Wqc, Wkc, Wvc, Woc, vs};
        cvt_all<<<dim3((unsigned)(SZ / 2048), 1, 5), 256, 0, stream>>>(a);
    }
    {   // Q,K,V projections (bf16 out); V slice also accumulates column sums
        GemmArgs g0{Qc, Wqc, qb, nullptr, nullptr};
        GemmArgs g1{Kc, Wkc, kb, nullptr, nullptr};
        GemmArgs g2{Vc, Wvc, vb, nullptr, vs};
        bf16_gemm_nt<<<dim3(GX, GY, 3), 256, 0, stream>>>(g0, g1, g2);
    }
    sparse_attn<<<dim3(S2 / 2, BB), 768, 0, stream>>>(qb, kb, vb, vs, idx, ao);
    global_attn_part<<<dim3(NCH, 2, NH * BB), 256, 0, stream>>>(qb, kb, vb, part);
    global_attn_fin<<<dim3(2 * NH * BB), 64, 0, stream>>>(part, ao);
    {   // output projection (fp32 out)
        GemmArgs g{ao, Woc, nullptr, out, nullptr};
        bf16_gemm_nt<<<dim3(GX, GY, 1), 256, 0, stream>>>(g, g, g);
    }
}

// Round 8
// 192.623 us; speedup vs baseline: 1.0710x; 1.0710x over previous
//
#include <hip/hip_runtime.h>
#include <hip/hip_bf16.h>

#define S_LEN   2048
#define D_MODEL 768
#define NH      12
#define HD      64
#define NI      6
#define S2      2046
#define BB      2
#define NCH     8
#define CHK     256   // keys per chunk (NCH*CHK == S_LEN)
#define SPB     (S2 / 2)   // 1023 sparse row-pairs per batch

typedef unsigned short ushort_t;
typedef __attribute__((ext_vector_type(8))) short short8v;   // 8 bf16 = 16B
typedef __attribute__((ext_vector_type(4))) float f32x4;     // MFMA C/D frag

__device__ __forceinline__ unsigned short bf16_rne(float x) {
    union { float f; unsigned int u; } c; c.f = x;
    unsigned int u = c.u + 0x7fffu + ((c.u >> 16) & 1u);
    return (unsigned short)(u >> 16);
}
__device__ __forceinline__ float bf16_f(unsigned short h) {
    union { unsigned int u; float f; } c; c.u = ((unsigned int)h) << 16;
    return c.f;
}

__device__ __forceinline__ void gload16(const ushort_t* g, ushort_t* l) {
    __builtin_amdgcn_global_load_lds(
        (const __attribute__((address_space(1))) void*)g,
        (__attribute__((address_space(3))) void*)l, 16, 0, 0);
}

// -------- combined fp32->bf16 convert (QKV + weights) + vs zero-fill --------
struct CvtAll {
    const float* Q; const float* K; const float* V;
    const float* Wq; const float* Wk; const float* Wv; const float* Wo;
    ushort_t* Qc; ushort_t* Kc; ushort_t* Vc;
    ushort_t* Wqc; ushort_t* Wkc; ushort_t* Wvc; ushort_t* Woc;
    float* vs;
};

__global__ __launch_bounds__(256) void cvt_all(CvtAll a) {
    const int z = blockIdx.z;
    const int tid = threadIdx.x;
    if (z == 4) {
        if (blockIdx.x == 0)
            for (int i = tid; i < BB * D_MODEL; i += 256) a.vs[i] = 0.f;
        return;
    }
    const float* s; ushort_t* d; long i;
    if (z < 3) {
        s = (z == 0) ? a.Q : (z == 1) ? a.K : a.V;
        d = (z == 0) ? a.Qc : (z == 1) ? a.Kc : a.Vc;
        i = ((long)blockIdx.x * 256 + tid) * 8;
    } else {
        const long WSZ = (long)D_MODEL * D_MODEL;
        long f = ((long)blockIdx.x * 256 + tid) * 8;
        if (f >= 4 * WSZ) return;
        const int which = (int)(f / WSZ);
        i = f % WSZ;
        s = (which == 0) ? a.Wq : (which == 1) ? a.Wk : (which == 2) ? a.Wv : a.Wo;
        d = (which == 0) ? a.Wqc : (which == 1) ? a.Wkc : (which == 2) ? a.Wvc : a.Woc;
    }
    float4 v0 = *(const float4*)&s[i];
    float4 v1 = *(const float4*)&s[i + 4];
    short8v o;
    o[0] = (short)bf16_rne(v0.x); o[1] = (short)bf16_rne(v0.y);
    o[2] = (short)bf16_rne(v0.z); o[3] = (short)bf16_rne(v0.w);
    o[4] = (short)bf16_rne(v1.x); o[5] = (short)bf16_rne(v1.y);
    o[6] = (short)bf16_rne(v1.z); o[7] = (short)bf16_rne(v1.w);
    *(short8v*)&d[i] = o;
}

// ---------------- bf16 MFMA NT GEMM: C[M,N] = A[M,K] * W[N,K]^T ----------
// r6-proven: 128x128 tile, BK=32, ring-3 LDS, depth-2 prefetch, counted
// vmcnt(4). NEW (single delta): bijective XCD-chunked block swizzle.
struct GemmArgs { const ushort_t* A; const ushort_t* W; ushort_t* C; float* Cf; float* vs; };

constexpr int GK = 768, GN = 768, GBK = 32, GNT = GK / GBK;   // 24 K-steps
constexpr int GX = 6, GY = 32;                                // grid x,y (128x128 tiles)

__global__ __launch_bounds__(256) void bf16_gemm_nt(GemmArgs g0, GemmArgs g1, GemmArgs g2) {
    // bijective XCD-chunked swizzle (nwg = 576 or 192, both % 8 == 0)
    const int nwg = GX * GY * gridDim.z;
    int flat = (blockIdx.z * GY + blockIdx.y) * GX + blockIdx.x;
    flat = (flat & 7) * (nwg >> 3) + (flat >> 3);
    const int bz = flat / (GX * GY);
    const int rem = flat - bz * (GX * GY);
    const int by = rem / GX;
    const int bx = rem - by * GX;

    GemmArgs g = (bz == 0) ? g0 : ((bz == 1) ? g1 : g2);

    __shared__ ushort_t As[3][4096];   // 128 rows x 32 bf16, swizzled 16B blocks
    __shared__ ushort_t Bs[3][4096];

    const int tid  = threadIdx.x;
    const int lane = tid & 63;
    const int w    = tid >> 6;
    const int wm   = w & 1;
    const int wn   = w >> 1;
    const int bm   = by * 128;
    const int bn   = bx * 128;
    const int fr   = lane & 15;
    const int blkr = lane >> 4;        // logical 16B-block (k/8)

    f32x4 acc[4][4];
    #pragma unroll
    for (int i = 0; i < 4; ++i)
        #pragma unroll
        for (int j = 0; j < 4; ++j)
            acc[i][j] = (f32x4){0.f, 0.f, 0.f, 0.f};

    const int row0 = tid >> 2;                      // 0..63
    const int row1 = row0 + 64;                     // 64..127
    const int blk0 = (tid & 3) ^ ((row0 >> 1) & 3);
    const int blk1 = (tid & 3) ^ ((row1 >> 1) & 3);
    const ushort_t* Ag0 = g.A + (size_t)(bm + row0) * GK + blk0 * 8;
    const ushort_t* Ag1 = g.A + (size_t)(bm + row1) * GK + blk1 * 8;
    const ushort_t* Bg0 = g.W + (size_t)(bn + row0) * GK + blk0 * 8;
    const ushort_t* Bg1 = g.W + (size_t)(bn + row1) * GK + blk1 * 8;
    const int l0 = w * 512;
    const int l1 = 2048 + w * 512;

    int aoff[4], boff[4];
    #pragma unroll
    for (int i = 0; i < 4; ++i) {
        const int ra = wm * 64 + i * 16 + fr;
        aoff[i] = (ra * 4 + (blkr ^ ((ra >> 1) & 3))) * 8;
        const int rb = wn * 64 + i * 16 + fr;
        boff[i] = (rb * 4 + (blkr ^ ((rb >> 1) & 3))) * 8;
    }

    gload16(Ag0, &As[0][l0]); gload16(Ag1, &As[0][l1]);
    gload16(Bg0, &Bs[0][l0]); gload16(Bg1, &Bs[0][l1]);
    gload16(Ag0 + GBK, &As[1][l0]); gload16(Ag1 + GBK, &As[1][l1]);
    gload16(Bg0 + GBK, &Bs[1][l0]); gload16(Bg1 + GBK, &Bs[1][l1]);

    for (int t = 0; t < GNT; ++t) {
        if (t < GNT - 1) asm volatile("s_waitcnt vmcnt(4)" ::: "memory");
        else             asm volatile("s_waitcnt vmcnt(0)" ::: "memory");
        __builtin_amdgcn_s_barrier();

        if (t + 2 < GNT) {
            const int ko = (t + 2) * GBK;
            const int nb = (t + 2) % 3;
            gload16(Ag0 + ko, &As[nb][l0]); gload16(Ag1 + ko, &As[nb][l1]);
            gload16(Bg0 + ko, &Bs[nb][l0]); gload16(Bg1 + ko, &Bs[nb][l1]);
        }

        const ushort_t* as = As[t % 3];
        const ushort_t* bs = Bs[t % 3];
        short8v a[4], b[4];
        #pragma unroll
        for (int i = 0; i < 4; ++i) a[i] = *(const short8v*)&as[aoff[i]];
        #pragma unroll
        for (int i = 0; i < 4; ++i) b[i] = *(const short8v*)&bs[boff[i]];
        #pragma unroll
        for (int i = 0; i < 4; ++i)
            #pragma unroll
            for (int j = 0; j < 4; ++j)
                acc[i][j] = __builtin_amdgcn_mfma_f32_16x16x32_bf16(a[i], b[j], acc[i][j], 0, 0, 0);
    }

    const int crow0 = bm + wm * 64 + ((lane >> 4) << 2);
    const int ccol0 = bn + wn * 64 + fr;
    if (g.Cf) {
        #pragma unroll
        for (int i = 0; i < 4; ++i)
            #pragma unroll
            for (int j = 0; j < 4; ++j)
                #pragma unroll
                for (int r = 0; r < 4; ++r)
                    g.Cf[(size_t)(crow0 + i * 16 + r) * GN + ccol0 + j * 16] = acc[i][j][r];
    } else {
        #pragma unroll
        for (int i = 0; i < 4; ++i)
            #pragma unroll
            for (int j = 0; j < 4; ++j)
                #pragma unroll
                for (int r = 0; r < 4; ++r)
                    g.C[(size_t)(crow0 + i * 16 + r) * GN + ccol0 + j * 16] = bf16_rne(acc[i][j][r]);
        if (g.vs) {   // fused V column-sum over bf16-rounded outputs
            const int bsel = (bm >= S_LEN) ? 1 : 0;
            #pragma unroll
            for (int j = 0; j < 4; ++j) {
                float part = 0.f;
                #pragma unroll
                for (int i = 0; i < 4; ++i)
                    #pragma unroll
                    for (int r = 0; r < 4; ++r)
                        part += bf16_f(bf16_rne(acc[i][j][r]));
                atomicAdd(&g.vs[bsel * D_MODEL + ccol0 + j * 16], part);
            }
        }
    }
}

// ------- fused attention: sparse rows (2/block) + global-row partials -------
// grid.x = SPB*BB (sparse) + NCH*2*NH*BB (part blocks); 768 threads.
__global__ __launch_bounds__(768) void attn_fused(
    const ushort_t* __restrict__ q, const ushort_t* __restrict__ k, const ushort_t* __restrict__ v,
    const float* __restrict__ vsum, const int* __restrict__ idx,
    float* __restrict__ part, ushort_t* __restrict__ ao) {
    const int bid = blockIdx.x;
    const int tid = threadIdx.x;

    __shared__ float qs[HD];
    __shared__ float ps[CHK];
    __shared__ float red[8];
    __shared__ float redv[96][72];

    if (bid < SPB * BB) {
        // ---------------- sparse path ----------------
        const int b = bid & 1;
        const int i0 = (bid >> 1) * 2;   // idx rows i0, i0+1 -> pos i0+1, i0+2
        const int c = tid;               // channel 0..767 (wave == head)

        int id[2][NI];
        #pragma unroll
        for (int r = 0; r < 2; ++r)
            #pragma unroll
            for (int j = 0; j < NI; ++j) id[r][j] = idx[(i0 + r) * NI + j];
        bool dup[2][NI];
        #pragma unroll
        for (int r = 0; r < 2; ++r)
            #pragma unroll
            for (int j = 0; j < NI; ++j) {
                bool d = false;
                #pragma unroll
                for (int j2 = 0; j2 < NI; ++j2)
                    if (j2 < j) d = d || (id[r][j2] == id[r][j]);
                dup[r][j] = d;
            }

        const size_t rb0 = ((size_t)(b * S_LEN + i0 + 1)) * D_MODEL + c;
        const float qv0 = bf16_f(q[rb0]);
        const float qv1 = bf16_f(q[rb0 + D_MODEL]);

        float kv[2][NI], vv[2][NI];
        #pragma unroll
        for (int r = 0; r < 2; ++r)
            #pragma unroll
            for (int j = 0; j < NI; ++j) {
                const size_t kb = ((size_t)(b * S_LEN + id[r][j])) * D_MODEL + c;
                kv[r][j] = bf16_f(k[kb]);
                vv[r][j] = bf16_f(v[kb]);
            }

        float p[2][NI];
        #pragma unroll
        for (int j = 0; j < NI; ++j) { p[0][j] = qv0 * kv[0][j]; p[1][j] = qv1 * kv[1][j]; }

        #pragma unroll
        for (int off = 32; off; off >>= 1) {
            #pragma unroll
            for (int r = 0; r < 2; ++r)
                #pragma unroll
                for (int j = 0; j < NI; ++j) p[r][j] += __shfl_xor(p[r][j], off);
        }

        const float vsc = vsum[b * D_MODEL + c];
        #pragma unroll
        for (int r = 0; r < 2; ++r) {
            float acc = vsc;
            float Z = 0.f;
            int u = 0;
            #pragma unroll
            for (int j = 0; j < NI; ++j) {
                if (dup[r][j]) continue;
                float e = expf(p[r][j] * 0.125f);
                Z += e;
                u += 1;
                acc += (e - 1.f) * vv[r][j];
            }
            Z += (float)(S_LEN - u);
            ao[rb0 + (size_t)r * D_MODEL] = bf16_rne(acc / Z);
        }
        return;
    }

    // ---------------- global-row partials path ----------------
    const int pid = bid - SPB * BB;
    const int ch = pid & 7;
    const int rowsel = (pid >> 3) & 1;
    const int hb = pid >> 4;             // 0..NH*BB-1
    const int h = hb % NH;
    const int b = hb / NH;
    const int row = rowsel ? (S_LEN - 1) : 0;

    if (tid < HD) qs[tid] = bf16_f(q[((size_t)(b * S_LEN + row)) * D_MODEL + h * HD + tid]);
    __syncthreads();

    float s = 0.f;
    if (tid < CHK) {
        const int t = ch * CHK + tid;
        const ushort_t* kp = &k[((size_t)(b * S_LEN + t)) * D_MODEL + h * HD];
        #pragma unroll
        for (int dd = 0; dd < 8; ++dd) {
            short8v kk = *(const short8v*)&kp[dd * 8];
            #pragma unroll
            for (int e = 0; e < 8; ++e)
                s += qs[dd * 8 + e] * bf16_f((unsigned short)kk[e]);
        }
        s *= 0.125f;
    }

    float m = s;
    #pragma unroll
    for (int off = 32; off; off >>= 1) m = fmaxf(m, __shfl_xor(m, off));
    if (tid < CHK && (tid & 63) == 0) red[tid >> 6] = m;
    __syncthreads();
    m = fmaxf(fmaxf(red[0], red[1]), fmaxf(red[2], red[3]));

    float e = (tid < CHK) ? expf(s - m) : 0.f;
    if (tid < CHK) ps[tid] = e;
    float zp = e;
    #pragma unroll
    for (int off = 32; off; off >>= 1) zp += __shfl_xor(zp, off);
    if (tid < CHK && (tid & 63) == 0) red[4 + (tid >> 6)] = zp;
    __syncthreads();
    const float E = red[4] + red[5] + red[6] + red[7];

    // PV with all 768 threads: 96 key-groups x 8-channel vectors
    const int g8 = tid >> 3;          // 0..95
    const int d8 = (tid & 7) * 8;     // 0,8,...,56
    float a8[8] = {};
    for (int tt = g8; tt < CHK; tt += 96) {
        const float wgt = ps[tt];
        short8v v8 = *(const short8v*)&v[((size_t)(b * S_LEN + ch * CHK + tt)) * D_MODEL + h * HD + d8];
        #pragma unroll
        for (int e2 = 0; e2 < 8; ++e2)
            a8[e2] += wgt * bf16_f((unsigned short)v8[e2]);
    }
    #pragma unroll
    for (int e2 = 0; e2 < 8; ++e2) redv[g8][d8 + e2] = a8[e2];
    __syncthreads();
    if (tid < HD) {
        float o = 0.f;
        #pragma unroll
        for (int gg = 0; gg < 96; ++gg) o += redv[gg][tid];
        float* pr = part + ((size_t)((hb * 2 + rowsel) * NCH + ch)) * (HD + 2);
        pr[2 + tid] = o;
        if (tid == 0) { pr[0] = m; pr[1] = E; }
    }
}

__global__ __launch_bounds__(64) void global_attn_fin(
    const float* __restrict__ part, ushort_t* __restrict__ ao) {
    const int rb = blockIdx.x;
    const int rowsel = rb & 1;
    const int hb = rb >> 1;
    const int h = hb % NH;
    const int b = hb / NH;
    const int row = rowsel ? (S_LEN - 1) : 0;
    const int d = threadIdx.x;

    const float* pr = part + (size_t)rb * NCH * (HD + 2);
    float M = -1e30f;
    #pragma unroll
    for (int c = 0; c < NCH; ++c) M = fmaxf(M, pr[c * (HD + 2)]);
    float Z = 0.f, acc = 0.f;
    #pragma unroll
    for (int c = 0; c < NCH; ++c) {
        float wgt = expf(pr[c * (HD + 2)] - M);
        Z   += pr[c * (HD + 2) + 1] * wgt;
        acc += pr[c * (HD + 2) + 2 + d] * wgt;
    }
    ao[((size_t)(b * S_LEN + row)) * D_MODEL + h * HD + d] = bf16_rne(acc / Z);
}

// ---------------- launch ----------------
extern "C" void kernel_launch(void* const* d_in, const int* in_sizes, int n_in,
                              void* d_out, int out_size, void* d_ws, size_t ws_size,
                              hipStream_t stream) {
    const float* Q  = (const float*)d_in[0];
    const float* K  = (const float*)d_in[1];
    const float* V  = (const float*)d_in[2];
    const float* Wq = (const float*)d_in[3];
    const float* Wk = (const float*)d_in[4];
    const float* Wv = (const float*)d_in[5];
    const float* Wo = (const float*)d_in[6];
    const int*  idx = (const int*)d_in[7];
    float* out = (float*)d_out;

    const size_t SZ  = (size_t)BB * S_LEN * D_MODEL;   // 3,145,728
    const size_t WSZ = (size_t)D_MODEL * D_MODEL;      // 589,824

    ushort_t* Qc  = (ushort_t*)d_ws;
    ushort_t* Kc  = Qc  + SZ;
    ushort_t* Vc  = Kc  + SZ;
    ushort_t* Wqc = Vc  + SZ;
    ushort_t* Wkc = Wqc + WSZ;
    ushort_t* Wvc = Wkc + WSZ;
    ushort_t* Woc = Wvc + WSZ;
    ushort_t* qb  = Woc + WSZ;
    ushort_t* kb  = qb  + SZ;
    ushort_t* vb  = kb  + SZ;
    ushort_t* ao  = vb  + SZ;
    float* vs   = (float*)(ao + SZ);
    float* part = vs + BB * D_MODEL;

    {   // one conversion + zero-fill dispatch
        CvtAll a{Q, K, V, Wq, Wk, Wv, Wo, Qc, Kc, Vc, Wqc, Wkc, Wvc, Woc, vs};
        cvt_all<<<dim3((unsigned)(SZ / 2048), 1, 5), 256, 0, stream>>>(a);
    }
    {   // Q,K,V projections (bf16 out); V slice also accumulates column sums
        GemmArgs g0{Qc, Wqc, qb, nullptr, nullptr};
        GemmArgs g1{Kc, Wkc, kb, nullptr, nullptr};
        GemmArgs g2{Vc, Wvc, vb, nullptr, vs};
        bf16_gemm_nt<<<dim3(GX, GY, 3), 256, 0, stream>>>(g0, g1, g2);
    }
    attn_fused<<<dim3(SPB * BB + NCH * 2 * NH * BB), 768, 0, stream>>>(
        qb, kb, vb, vs, idx, part, ao);
    global_attn_fin<<<dim3(2 * NH * BB), 64, 0, stream>>>(part, ao);
    {   // output projection (fp32 out)
        GemmArgs g{ao, Woc, nullptr, out, nullptr};
        bf16_gemm_nt<<<dim3(GX, GY, 1), 256, 0, stream>>>(g, g, g);
    }
}